// Round 15
// baseline (148.128 us; speedup 1.0000x reference)
//
#include <hip/hip_runtime.h>
#include <hip/hip_bf16.h>

#define E_ 8
#define B_ 8
#define S_ 2048
#define D_ 512
#define R_ 128
#define M_TOT (B_ * S_)   // 16384

typedef __attribute__((ext_vector_type(8))) short bf16x8;
typedef __attribute__((ext_vector_type(4))) float f32x4;
typedef __attribute__((ext_vector_type(4))) short s16x4;

__device__ __forceinline__ void gload_lds16(void* lds, const void* g) {
  __builtin_amdgcn_global_load_lds(
      (const __attribute__((address_space(1))) void*)g,
      (__attribute__((address_space(3))) void*)lds, 16, 0, 0);
}

// ---------------------------------------------------------------------------
// Fused prep kernel (R13): rot one-shot slab | W tail | x -> bf16 (nt loads)
// ---------------------------------------------------------------------------
#define ROT_B 32
#define WT_B 2048
#define CX_B 4096
__global__ __launch_bounds__(256) void prep_fused(
    const float* __restrict__ x, const float* __restrict__ theta,
    const float* __restrict__ pw, __hip_bfloat16* __restrict__ xb,
    __hip_bfloat16* __restrict__ Wb) {
  int blk = blockIdx.x;
  int t = threadIdx.x;
  if (blk < ROT_B) {
    __shared__ float cs[R_], ss[R_];
    __shared__ float Pch[128][130];
    __shared__ __hip_bfloat16 Wch[128][130];
    int e = blk >> 2;
    int r0 = (blk & 3) * 128;
    if (t < R_) {
      float a = tanhf(theta[e * R_ + t]) * 0.1f;
      cs[t] = cosf(a);
      ss[t] = sinf(a);
    }
    const float* Pe = pw + (size_t)e * D_ * D_;
    __hip_bfloat16* We = Wb + (size_t)e * D_ * D_;
#pragma unroll 8
    for (int it = 0; it < 64; ++it) {
      int row = it * 2 + (t >> 7);
      int col = t & 127;
      Pch[row][col] = Pe[(size_t)(r0 + row) * D_ + col];
    }
    if (t < 128) Pch[t][128] = Pe[(size_t)(r0 + t) * D_ + 128];
    __syncthreads();
    if (t < 128) {
      float u = Pch[t][0];
#pragma unroll 16
      for (int k = 0; k < R_; ++k) {
        float pj = Pch[t][k + 1];
        Wch[t][k + 1] = __float2bfloat16(cs[k] * pj - ss[k] * u);
        u = cs[k] * u + ss[k] * pj;
      }
      Wch[t][0] = __float2bfloat16(u);
    }
    __syncthreads();
#pragma unroll 8
    for (int it = 0; it < 64; ++it) {
      int row = it * 2 + (t >> 7);
      int col = t & 127;
      We[(size_t)(r0 + row) * D_ + col] = Wch[row][col];
    }
    if (t < 128) We[(size_t)(r0 + t) * D_ + 128] = Wch[t][128];
  } else if (blk < ROT_B + WT_B) {
    int g = (blk - ROT_B) * 256 + t;
    int gidx = g & 127;
    if (gidx < 32) return;
    float4 v = ((const float4*)pw)[g];
    union { short4 s; __hip_bfloat16 h[4]; } u;
    u.h[0] = __float2bfloat16(v.x);
    u.h[1] = __float2bfloat16(v.y);
    u.h[2] = __float2bfloat16(v.z);
    u.h[3] = __float2bfloat16(v.w);
    if (gidx > 32) {
      ((short4*)Wb)[g] = u.s;
    } else {
      Wb[(size_t)g * 4 + 1] = u.h[1];
      Wb[(size_t)g * 4 + 2] = u.h[2];
      Wb[(size_t)g * 4 + 3] = u.h[3];
    }
  } else {
    int i = (blk - ROT_B - WT_B) * 256 + t;
#pragma unroll
    for (int rep = 0; rep < 2; ++rep) {
      int idx = i + rep * (CX_B * 256);
      f32x4 v = __builtin_nontemporal_load(&((const f32x4*)x)[idx]);
      union { s16x4 s; __hip_bfloat16 h[4]; } u;
      u.h[0] = __float2bfloat16(v.x);
      u.h[1] = __float2bfloat16(v.y);
      u.h[2] = __float2bfloat16(v.z);
      u.h[3] = __float2bfloat16(v.w);
      ((s16x4*)xb)[idx] = u.s;
    }
  }
}

// ---------------------------------------------------------------------------
// GEMM: out[e] = Xb @ Wb[e]^T (NT). K-loop identical to R12/R13 (256x128
// block, 4 waves, BK=32 dbuf, counted vmcnt(6), 2 blocks/CU, XCD swizzle,
// setprio) — but MFMA operands SWAPPED: mfma(bfr, af, acc) yields the
// transposed fragment (m = lane&15, n = (lane>>4)*4 + q), so each lane's
// f32x4 acc is a CONTIGUOUS 16B chunk of the output row. Epilogue becomes
// direct nontemporal f32x4 stores: no LDS round-trip (was 8 MB/CU through
// the ~85-128 B/cyc LDS pipe = the R12 ceiling), no epilogue barriers,
// 64B-aligned sector writes (4 lanes/row/instruction, ni-frags adjacent).
// ---------------------------------------------------------------------------
__global__ __launch_bounds__(256, 2) void gemm_xw(
    const __hip_bfloat16* __restrict__ Xb,   // [M_TOT][512]
    const __hip_bfloat16* __restrict__ Wb,   // [E][512][512] rows=o, cols=d
    float* __restrict__ out)                 // [E][M_TOT][512]
{
  constexpr int BM = 256, BN = 128, BK = 32;
  constexpr int KD = D_, ND = D_;
  constexpr int NT = KD / BK;  // 16
  __shared__ __align__(16) __hip_bfloat16 As[2][BM * BK];  // 32 KB
  __shared__ __align__(16) __hip_bfloat16 Bs[2][BN * BK];  // 16 KB

  int bx = blockIdx.x;            // 2048 blocks
  int xcd = bx & 7, c = bx >> 3;  // chunk c in [0,256) per XCD
  int e = c >> 5;                 // 0..7  (e-major within XCD)
  int msub = (c >> 2) & 7;        // 0..7
  int nt = c & 3;                 // 0..3
  int mt = xcd * 8 + msub;        // 0..63

  int tid = threadIdx.x;
  int wave = tid >> 6, lane = tid & 63;
  int lr = lane & 15, lk = lane >> 4;
  int wm = wave >> 1, wn = wave & 1;   // 2x2 waves; wave-tile 128x64

  const __hip_bfloat16* Ag = Xb + (size_t)(mt * BM) * KD;
  const __hip_bfloat16* Bg = Wb + ((size_t)e * ND + (size_t)nt * BN) * KD;

  // staging: lane -> (row = lane>>2 of 16, chunk = lane&3); linear LDS dest.
  int srow = lane >> 2;
  int scol = (lane & 3) * 8;

  // fragment reads: addr = row*64B + lk*16B (bank-uniform at 64B stride)
  int aoff = (wm * 128 + lr) * BK + lk * 8;
  int boff = (wn * 64 + lr) * BK + lk * 8;

  f32x4 acc[8][4];
#pragma unroll
  for (int i = 0; i < 8; ++i)
#pragma unroll
    for (int j = 0; j < 4; ++j) acc[i][j] = (f32x4){0.f, 0.f, 0.f, 0.f};

  // per wave per tile: A 4 gloads (64 rows), B 2 gloads (32 rows) = 6 loads
#define STAGE(buf, t)                                                        \
  {                                                                          \
    _Pragma("unroll") for (int g = 0; g < 4; ++g) {                          \
      int rb = wave * 64 + g * 16;                                           \
      gload_lds16(&As[buf][rb * BK],                                         \
                  Ag + (size_t)(rb + srow) * KD + (t) * BK + scol);          \
    }                                                                        \
    _Pragma("unroll") for (int g = 0; g < 2; ++g) {                          \
      int rb = wave * 32 + g * 16;                                           \
      gload_lds16(&Bs[buf][rb * BK],                                         \
                  Bg + (size_t)(rb + srow) * KD + (t) * BK + scol);          \
    }                                                                        \
  }

  STAGE(0, 0);
  STAGE(1, 1);

#pragma unroll
  for (int t = 0; t < NT; ++t) {
    int buf = t & 1;
    // tile t resident once <=6 newer loads (tile t+1) remain in flight
    if (t < NT - 1) {
      asm volatile("s_waitcnt vmcnt(6)" ::: "memory");
    } else {
      asm volatile("s_waitcnt vmcnt(0)" ::: "memory");
    }
    __builtin_amdgcn_s_barrier();   // tile t visible to all 4 waves

    bf16x8 af[8], bfr[4];
#pragma unroll
    for (int ni = 0; ni < 4; ++ni)
      bfr[ni] = *(const bf16x8*)&Bs[buf][boff + ni * 16 * BK];
#pragma unroll
    for (int mi = 0; mi < 8; ++mi)
      af[mi] = *(const bf16x8*)&As[buf][aoff + mi * 16 * BK];
    __builtin_amdgcn_s_setprio(1);
#pragma unroll
    for (int mi = 0; mi < 8; ++mi)
#pragma unroll
      for (int ni = 0; ni < 4; ++ni)
        acc[mi][ni] = __builtin_amdgcn_mfma_f32_16x16x32_bf16(
            bfr[ni], af[mi], acc[mi][ni], 0, 0, 0);   // SWAPPED operands
    __builtin_amdgcn_s_setprio(0);

    // all ds_reads of this tile drained before DMA may overwrite the slot
    asm volatile("s_waitcnt lgkmcnt(0)" ::: "memory");
    __builtin_amdgcn_sched_barrier(0);
    __builtin_amdgcn_s_barrier();
    if (t + 2 < NT) STAGE(buf, t + 2);
  }
#undef STAGE

  // ---- direct-store epilogue (no LDS) ----
  // Swapped-operand C/D layout: element (m = lane&15, n = (lane>>4)*4 + q)
  // -> each lane's f32x4 is 4 consecutive n at one row m: one 16B chunk.
  size_t obase = (size_t)e * M_TOT * ND;
  int row0 = mt * BM + wm * 128;
  int col0 = nt * BN + wn * 64;
  int m_l = lr;        // lane&15
  int n_l = lk * 4;    // (lane>>4)*4
#pragma unroll
  for (int mi = 0; mi < 8; ++mi) {
    size_t rbase = obase + (size_t)(row0 + mi * 16 + m_l) * ND + col0 + n_l;
#pragma unroll
    for (int ni = 0; ni < 4; ++ni)
      __builtin_nontemporal_store(acc[mi][ni], (f32x4*)&out[rbase + ni * 16]);
  }
}

extern "C" void kernel_launch(void* const* d_in, const int* in_sizes, int n_in,
                              void* d_out, int out_size, void* d_ws, size_t ws_size,
                              hipStream_t stream) {
  const float* x = (const float*)d_in[0];        // [B][S][D] f32
  const float* theta = (const float*)d_in[1];    // [E][R] f32
  const float* proj_w = (const float*)d_in[2];   // [E][D][D] f32
  float* out = (float*)d_out;                    // [E][B][S][D] f32

  __hip_bfloat16* xb = (__hip_bfloat16*)d_ws;                          // 16 MB
  __hip_bfloat16* Wb = (__hip_bfloat16*)((char*)d_ws +
                        (size_t)M_TOT * D_ * sizeof(__hip_bfloat16));  // 4 MB

  hipLaunchKernelGGL(prep_fused, dim3(ROT_B + WT_B + CX_B), dim3(256), 0,
                     stream, x, theta, proj_w, xb, Wb);
  // grid: (M_TOT/256)=64 mt  x  8 e  x  (512/128)=4 nt  = 2048 blocks
  hipLaunchKernelGGL(gemm_xw, dim3(2048), dim3(256), 0, stream, xb, Wb, out);
}

// Round 16
// 103.692 us; speedup vs baseline: 1.4285x; 1.4285x over previous
//
#include <hip/hip_runtime.h>
#include <hip/hip_bf16.h>

#define E_ 8
#define B_ 8
#define S_ 2048
#define D_ 512
#define R_ 128
#define M_TOT (B_ * S_)   // 16384

typedef __attribute__((ext_vector_type(8))) short bf16x8;
typedef __attribute__((ext_vector_type(4))) float f32x4;
typedef __attribute__((ext_vector_type(4))) short s16x4;

__device__ __forceinline__ void gload_lds16(void* lds, const void* g) {
  __builtin_amdgcn_global_load_lds(
      (const __attribute__((address_space(1))) void*)g,
      (__attribute__((address_space(3))) void*)lds, 16, 0, 0);
}

// ---------------------------------------------------------------------------
// Fused prep kernel (R13): rot one-shot slab | W tail | x -> bf16 (nt loads)
// ---------------------------------------------------------------------------
#define ROT_B 32
#define WT_B 2048
#define CX_B 4096
__global__ __launch_bounds__(256) void prep_fused(
    const float* __restrict__ x, const float* __restrict__ theta,
    const float* __restrict__ pw, __hip_bfloat16* __restrict__ xb,
    __hip_bfloat16* __restrict__ Wb) {
  int blk = blockIdx.x;
  int t = threadIdx.x;
  if (blk < ROT_B) {
    __shared__ float cs[R_], ss[R_];
    __shared__ float Pch[128][130];
    __shared__ __hip_bfloat16 Wch[128][130];
    int e = blk >> 2;
    int r0 = (blk & 3) * 128;
    if (t < R_) {
      float a = tanhf(theta[e * R_ + t]) * 0.1f;
      cs[t] = cosf(a);
      ss[t] = sinf(a);
    }
    const float* Pe = pw + (size_t)e * D_ * D_;
    __hip_bfloat16* We = Wb + (size_t)e * D_ * D_;
#pragma unroll 8
    for (int it = 0; it < 64; ++it) {
      int row = it * 2 + (t >> 7);
      int col = t & 127;
      Pch[row][col] = Pe[(size_t)(r0 + row) * D_ + col];
    }
    if (t < 128) Pch[t][128] = Pe[(size_t)(r0 + t) * D_ + 128];
    __syncthreads();
    if (t < 128) {
      float u = Pch[t][0];
#pragma unroll 16
      for (int k = 0; k < R_; ++k) {
        float pj = Pch[t][k + 1];
        Wch[t][k + 1] = __float2bfloat16(cs[k] * pj - ss[k] * u);
        u = cs[k] * u + ss[k] * pj;
      }
      Wch[t][0] = __float2bfloat16(u);
    }
    __syncthreads();
#pragma unroll 8
    for (int it = 0; it < 64; ++it) {
      int row = it * 2 + (t >> 7);
      int col = t & 127;
      We[(size_t)(r0 + row) * D_ + col] = Wch[row][col];
    }
    if (t < 128) We[(size_t)(r0 + t) * D_ + 128] = Wch[t][128];
  } else if (blk < ROT_B + WT_B) {
    int g = (blk - ROT_B) * 256 + t;
    int gidx = g & 127;
    if (gidx < 32) return;
    float4 v = ((const float4*)pw)[g];
    union { short4 s; __hip_bfloat16 h[4]; } u;
    u.h[0] = __float2bfloat16(v.x);
    u.h[1] = __float2bfloat16(v.y);
    u.h[2] = __float2bfloat16(v.z);
    u.h[3] = __float2bfloat16(v.w);
    if (gidx > 32) {
      ((short4*)Wb)[g] = u.s;
    } else {
      Wb[(size_t)g * 4 + 1] = u.h[1];
      Wb[(size_t)g * 4 + 2] = u.h[2];
      Wb[(size_t)g * 4 + 3] = u.h[3];
    }
  } else {
    int i = (blk - ROT_B - WT_B) * 256 + t;
#pragma unroll
    for (int rep = 0; rep < 2; ++rep) {
      int idx = i + rep * (CX_B * 256);
      f32x4 v = __builtin_nontemporal_load(&((const f32x4*)x)[idx]);
      union { s16x4 s; __hip_bfloat16 h[4]; } u;
      u.h[0] = __float2bfloat16(v.x);
      u.h[1] = __float2bfloat16(v.y);
      u.h[2] = __float2bfloat16(v.z);
      u.h[3] = __float2bfloat16(v.w);
      ((s16x4*)xb)[idx] = u.s;
    }
  }
}

// ---------------------------------------------------------------------------
// GEMM: out[e] = Xb @ Wb[e]^T (NT). K-loop = R12/R13 (256x128 block, 4 waves,
// BK=32 dbuf, counted vmcnt(6), 2 blocks/CU, XCD swizzle, setprio) with
// SWAPPED mfma operands (layout proven correct in R15): lane's acc[mi][ni]
// = contiguous 16B of row (m=lr, n=lk*4+q). Epilogue keeps R13's full-line
// staged write path (512B-contiguous nt stores — worth ~40us, R15 lesson)
// but stages via ds_write_b128 (8 instr/thread instead of 128 scalar b32):
// stride 132 -> (lr+lk)%8 spreads 64 lanes uniformly 8 per 16B-slot (b128
// minimum, conflict-free).
// ---------------------------------------------------------------------------
__global__ __launch_bounds__(256, 2) void gemm_xw(
    const __hip_bfloat16* __restrict__ Xb,   // [M_TOT][512]
    const __hip_bfloat16* __restrict__ Wb,   // [E][512][512] rows=o, cols=d
    float* __restrict__ out)                 // [E][M_TOT][512]
{
  constexpr int BM = 256, BN = 128, BK = 32;
  constexpr int KD = D_, ND = D_;
  constexpr int NT = KD / BK;  // 16
  __shared__ __align__(16) char smem[49152];
  __hip_bfloat16 (*As)[BM * BK] =
      (__hip_bfloat16 (*)[BM * BK]) & smem[0];         // 2 x 16 KB
  __hip_bfloat16 (*Bs)[BN * BK] =
      (__hip_bfloat16 (*)[BN * BK]) & smem[32768];     // 2 x 8 KB
  float* Lep = (float*)&smem[0];                       // epilogue: 2x32x132 f32

  int bx = blockIdx.x;            // 2048 blocks
  int xcd = bx & 7, c = bx >> 3;  // chunk c in [0,256) per XCD
  int e = c >> 5;                 // 0..7  (e-major within XCD)
  int msub = (c >> 2) & 7;        // 0..7
  int nt = c & 3;                 // 0..3
  int mt = xcd * 8 + msub;        // 0..63

  int tid = threadIdx.x;
  int wave = tid >> 6, lane = tid & 63;
  int lr = lane & 15, lk = lane >> 4;
  int wm = wave >> 1, wn = wave & 1;   // 2x2 waves; wave-tile 128x64

  const __hip_bfloat16* Ag = Xb + (size_t)(mt * BM) * KD;
  const __hip_bfloat16* Bg = Wb + ((size_t)e * ND + (size_t)nt * BN) * KD;

  // staging: lane -> (row = lane>>2 of 16, chunk = lane&3); linear LDS dest.
  int srow = lane >> 2;
  int scol = (lane & 3) * 8;

  // fragment reads: addr = row*64B + lk*16B (bank-uniform at 64B stride)
  int aoff = (wm * 128 + lr) * BK + lk * 8;
  int boff = (wn * 64 + lr) * BK + lk * 8;

  f32x4 acc[8][4];
#pragma unroll
  for (int i = 0; i < 8; ++i)
#pragma unroll
    for (int j = 0; j < 4; ++j) acc[i][j] = (f32x4){0.f, 0.f, 0.f, 0.f};

  // per wave per tile: A 4 gloads (64 rows), B 2 gloads (32 rows) = 6 loads
#define STAGE(buf, t)                                                        \
  {                                                                          \
    _Pragma("unroll") for (int g = 0; g < 4; ++g) {                          \
      int rb = wave * 64 + g * 16;                                           \
      gload_lds16(&As[buf][rb * BK],                                         \
                  Ag + (size_t)(rb + srow) * KD + (t) * BK + scol);          \
    }                                                                        \
    _Pragma("unroll") for (int g = 0; g < 2; ++g) {                          \
      int rb = wave * 32 + g * 16;                                           \
      gload_lds16(&Bs[buf][rb * BK],                                         \
                  Bg + (size_t)(rb + srow) * KD + (t) * BK + scol);          \
    }                                                                        \
  }

  STAGE(0, 0);
  STAGE(1, 1);

#pragma unroll
  for (int t = 0; t < NT; ++t) {
    int buf = t & 1;
    // tile t resident once <=6 newer loads (tile t+1) remain in flight
    if (t < NT - 1) {
      asm volatile("s_waitcnt vmcnt(6)" ::: "memory");
    } else {
      asm volatile("s_waitcnt vmcnt(0)" ::: "memory");
    }
    __builtin_amdgcn_s_barrier();   // tile t visible to all 4 waves

    bf16x8 af[8], bfr[4];
#pragma unroll
    for (int ni = 0; ni < 4; ++ni)
      bfr[ni] = *(const bf16x8*)&Bs[buf][boff + ni * 16 * BK];
#pragma unroll
    for (int mi = 0; mi < 8; ++mi)
      af[mi] = *(const bf16x8*)&As[buf][aoff + mi * 16 * BK];
    __builtin_amdgcn_s_setprio(1);
#pragma unroll
    for (int mi = 0; mi < 8; ++mi)
#pragma unroll
      for (int ni = 0; ni < 4; ++ni)
        acc[mi][ni] = __builtin_amdgcn_mfma_f32_16x16x32_bf16(
            bfr[ni], af[mi], acc[mi][ni], 0, 0, 0);   // swapped (R15-proven)
    __builtin_amdgcn_s_setprio(0);

    // all ds_reads of this tile drained before DMA may overwrite the slot
    asm volatile("s_waitcnt lgkmcnt(0)" ::: "memory");
    __builtin_amdgcn_sched_barrier(0);
    __builtin_amdgcn_s_barrier();
    if (t + 2 < NT) STAGE(buf, t + 2);
  }
#undef STAGE

  // ---- write-coalesced epilogue: b128 staging + 512B-line nt stores ----
  // Swapped layout: acc[mi][ni] = out rows (row0+mi*16+lr),
  // cols (col0+ni*16+lk*4 .. +4) — one f32x4 = one ds_write_b128.
  size_t obase = (size_t)e * M_TOT * ND;
  int row0 = mt * BM;
  int col0 = nt * BN;
  float* Lh = Lep + (size_t)wm * (32 * 132);
#pragma unroll
  for (int r = 0; r < 4; ++r) {
#pragma unroll
    for (int m2 = 0; m2 < 2; ++m2) {
      int mi = 2 * r + m2;
#pragma unroll
      for (int ni = 0; ni < 4; ++ni)
        *(f32x4*)&Lh[(m2 * 16 + lr) * 132 + wn * 64 + ni * 16 + lk * 4] =
            acc[mi][ni];
    }
    __builtin_amdgcn_s_barrier();
    // readback: wave wn covers LDS rows [wn*16, +16); lanes 0..31 = one row
    // (512B contiguous), lanes 32..63 = next row.
#pragma unroll
    for (int j = 0; j < 8; ++j) {
      int lrow = wn * 16 + j * 2 + (lane >> 5);
      int lc4 = lane & 31;
      f32x4 v = *(const f32x4*)&Lh[lrow * 132 + lc4 * 4];
      int grow = row0 + wm * 128 + r * 32 + lrow;
      __builtin_nontemporal_store(
          v, (f32x4*)&out[obase + (size_t)grow * ND + col0 + lc4 * 4]);
    }
    __builtin_amdgcn_s_barrier();
  }
}

extern "C" void kernel_launch(void* const* d_in, const int* in_sizes, int n_in,
                              void* d_out, int out_size, void* d_ws, size_t ws_size,
                              hipStream_t stream) {
  const float* x = (const float*)d_in[0];        // [B][S][D] f32
  const float* theta = (const float*)d_in[1];    // [E][R] f32
  const float* proj_w = (const float*)d_in[2];   // [E][D][D] f32
  float* out = (float*)d_out;                    // [E][B][S][D] f32

  __hip_bfloat16* xb = (__hip_bfloat16*)d_ws;                          // 16 MB
  __hip_bfloat16* Wb = (__hip_bfloat16*)((char*)d_ws +
                        (size_t)M_TOT * D_ * sizeof(__hip_bfloat16));  // 4 MB

  hipLaunchKernelGGL(prep_fused, dim3(ROT_B + WT_B + CX_B), dim3(256), 0,
                     stream, x, theta, proj_w, xb, Wb);
  // grid: (M_TOT/256)=64 mt  x  8 e  x  (512/128)=4 nt  = 2048 blocks
  hipLaunchKernelGGL(gemm_xw, dim3(2048), dim3(256), 0, stream, xb, Wb, out);
}